// Round 6
// baseline (90.754 us; speedup 1.0000x reference)
//
#include <hip/hip_runtime.h>

// Bilateral slicing (HDRNet).
// grid  : [B=8][C=12][D=8][Hg=16][Wg=16] fp32  (logical [B,Hg,Wg,D,C] after ref transpose)
// guide : [B=8][1][H=1024][W=1024] fp32 in [0,1)
// out   : [B=8][C=12][H=1024][W=1024] fp32
//
// R6 = R5 with ONE change: XCD-contiguous block remap. With the default
// grid(1024,8) mapping, XCD = y%8, so each XCD advances 96 write streams in
// scattered 4KB bursts (32KB stride). Remap so XCD k owns batch k and sweeps
// y sequentially -> 12 long sequential 4MB write streams per XCD.

#define BB 8
#define CC 12
#define DD 8
#define HG 16
#define WG 16
#define HH 1024
#define WW 1024
#define ZP 9                      // padded z-stride (bank-conflict-free staging writes)
#define CSTRIDE (WG * ZP)         // 144 words per channel
#define NBLK (BB * HH)            // 8192, % 8 == 0 -> bijective swizzle

__global__ __launch_bounds__(256) void slice_kernel(
    const float* __restrict__ grid,
    const float* __restrict__ guide,
    float* __restrict__ out)
{
    // y-pre-interpolated grid slice for this row: [c][xg][z], z padded to 9
    __shared__ float S[CC * CSTRIDE];   // 1728 floats = 6.9 KB

    // XCD-contiguous swizzle (bijective, NBLK%8==0): XCD k = n%8 owns n2 in
    // [k*1024,(k+1)*1024) = batch k, y swept 0..1023 in dispatch order.
    const int n   = blockIdx.x;
    const int n2  = (n & 7) * (NBLK / 8) + (n >> 3);
    const int b   = n2 >> 10;     // n2 / 1024
    const int y   = n2 & 1023;
    const int tid = threadIdx.x;  // 0..255

    // ---- y interpolation (block-uniform), clamped-base form ----
    const float gy  = ((float)y + 0.5f) * (1.0f / 64.0f);
    const float ty  = gy - 0.5f;
    const int   yb  = (int)fminf(fmaxf(floorf(ty), 0.0f), (float)(HG - 2));
    const float wy1 = fminf(fmaxf(ty - (float)yb, 0.0f), 1.0f);
    const float wy0 = 1.0f - wy1;

    // ---- coalesced grid staging (same as R5) ----
    const float* gb = grid + (size_t)b * (CC * DD * HG * WG);
    #pragma unroll
    for (int k = 0; k < 3; ++k) {
        const int idx   = tid + k * 256;      // 0..767
        const int chunk = idx >> 3;           // 0..95
        const int lane8 = idx & 7;
        const int c = chunk >> 3;
        const int z = chunk & 7;
        const float4 v = *(const float4*)(gb + (size_t)(c * DD + z) * (HG * WG)
                                          + yb * WG + lane8 * 4);
        const float4 o = make_float4(__shfl_xor(v.x, 4),
                                     __shfl_xor(v.y, 4),
                                     __shfl_xor(v.z, 4),
                                     __shfl_xor(v.w, 4));
        if (lane8 < 4) {   // this lane holds row yb, partner holds yb+1
            const int xg0 = lane8 * 4;
            float* dst = &S[c * CSTRIDE + xg0 * ZP + z];
            dst[0 * ZP] = wy0 * v.x + wy1 * o.x;
            dst[1 * ZP] = wy0 * v.y + wy1 * o.y;
            dst[2 * ZP] = wy0 * v.z + wy1 * o.z;
            dst[3 * ZP] = wy0 * v.w + wy1 * o.w;
        }
    }
    __syncthreads();

    // ---- per-thread: 4 consecutive pixels, float4 I/O ----
    const int x0 = tid * 4;
    const float4 g4 = *(const float4*)(guide + ((size_t)b * HH + y) * WW + x0);
    const float gvals[4] = {g4.x, g4.y, g4.z, g4.w};

    float w00[4], w01[4], w10[4], w11[4];
    int a0[4];
    #pragma unroll
    for (int p = 0; p < 4; ++p) {
        // z interpolation, clamped-base form
        const float gz  = gvals[p] * 8.0f;
        const float tz  = gz - 0.5f;
        const int   zb  = (int)fminf(fmaxf(floorf(tz), 0.0f), (float)(DD - 2));
        const float wz1 = fminf(fmaxf(tz - (float)zb, 0.0f), 1.0f);
        const float wz0 = 1.0f - wz1;

        // x interpolation, clamped-base form
        const float gx  = ((float)(x0 + p) + 0.5f) * (1.0f / 64.0f);
        const float tx  = gx - 0.5f;
        const int   xb  = (int)fminf(fmaxf(floorf(tx), 0.0f), (float)(WG - 2));
        const float wx1 = fminf(fmaxf(tx - (float)xb, 0.0f), 1.0f);
        const float wx0 = 1.0f - wx1;

        w00[p] = wx0 * wz0;
        w01[p] = wx0 * wz1;
        w10[p] = wx1 * wz0;
        w11[p] = wx1 * wz1;
        a0[p]  = xb * ZP + zb;
    }

    float* outp = out + ((size_t)(b * CC) * HH + y) * WW + x0;

    #pragma unroll
    for (int c = 0; c < CC; ++c) {
        const float* base = S + c * CSTRIDE;
        float r[4];
        #pragma unroll
        for (int p = 0; p < 4; ++p) {
            const float va0 = base[a0[p]];          // (xb,   zb)
            const float va1 = base[a0[p] + 1];      // (xb,   zb+1)
            const float vb0 = base[a0[p] + ZP];     // (xb+1, zb)
            const float vb1 = base[a0[p] + ZP + 1]; // (xb+1, zb+1)
            r[p] = w00[p] * va0 + w01[p] * va1 + w10[p] * vb0 + w11[p] * vb1;
        }
        *(float4*)(outp + (size_t)c * (HH * WW)) = make_float4(r[0], r[1], r[2], r[3]);
    }
}

extern "C" void kernel_launch(void* const* d_in, const int* in_sizes, int n_in,
                              void* d_out, int out_size, void* d_ws, size_t ws_size,
                              hipStream_t stream) {
    const float* grid  = (const float*)d_in[0];  // 8*12*8*16*16
    const float* guide = (const float*)d_in[1];  // 8*1*1024*1024
    float* out = (float*)d_out;                  // 8*12*1024*1024

    slice_kernel<<<dim3(NBLK), dim3(256), 0, stream>>>(grid, guide, out);
}

// Round 8
// 81.909 us; speedup vs baseline: 1.1080x; 1.1080x over previous
//
#include <hip/hip_runtime.h>

// Bilateral slicing (HDRNet).
// grid  : [B=8][C=12][D=8][Hg=16][Wg=16] fp32  (logical [B,Hg,Wg,D,C] after ref transpose)
// guide : [B=8][1][H=1024][W=1024] fp32 in [0,1)
// out   : [B=8][C=12][H=1024][W=1024] fp32
//
// R7b = R5 (grid(1024,8) mapping — R6 proved the XCD-contiguous remap hurts)
//  + nontemporal output stores (403 MB never re-read; skip L2/L3 churn)
//  + guide load hoisted above staging (HBM latency hides under staging latency)
//  (R7a failed to compile: __builtin_nontemporal_store needs a native vector
//   type, not HIP_vector_type — use ext_vector_type(4).)

#define BB 8
#define CC 12
#define DD 8
#define HG 16
#define WG 16
#define HH 1024
#define WW 1024
#define ZP 9                      // padded z-stride (bank-conflict-free staging writes)
#define CSTRIDE (WG * ZP)         // 144 words per channel

typedef float float4v __attribute__((ext_vector_type(4)));

__global__ __launch_bounds__(256) void slice_kernel(
    const float* __restrict__ grid,
    const float* __restrict__ guide,
    float* __restrict__ out)
{
    // y-pre-interpolated grid slice for this row: [c][xg][z], z padded to 9
    __shared__ float S[CC * CSTRIDE];   // 1728 floats = 6.9 KB

    const int y   = blockIdx.x;   // 0..1023
    const int b   = blockIdx.y;   // 0..7
    const int tid = threadIdx.x;  // 0..255

    // ---- guide load FIRST: issue before staging so its latency overlaps ----
    const int x0 = tid * 4;
    const float4 g4 = *(const float4*)(guide + ((size_t)b * HH + y) * WW + x0);

    // ---- y interpolation (block-uniform), clamped-base form ----
    const float gy  = ((float)y + 0.5f) * (1.0f / 64.0f);
    const float ty  = gy - 0.5f;
    const int   yb  = (int)fminf(fmaxf(floorf(ty), 0.0f), (float)(HG - 2));
    const float wy1 = fminf(fmaxf(ty - (float)yb, 0.0f), 1.0f);
    const float wy0 = 1.0f - wy1;

    // ---- coalesced grid staging (same as R5) ----
    const float* gb = grid + (size_t)b * (CC * DD * HG * WG);
    #pragma unroll
    for (int k = 0; k < 3; ++k) {
        const int idx   = tid + k * 256;      // 0..767
        const int chunk = idx >> 3;           // 0..95
        const int lane8 = idx & 7;
        const int c = chunk >> 3;
        const int z = chunk & 7;
        const float4 v = *(const float4*)(gb + (size_t)(c * DD + z) * (HG * WG)
                                          + yb * WG + lane8 * 4);
        const float4 o = make_float4(__shfl_xor(v.x, 4),
                                     __shfl_xor(v.y, 4),
                                     __shfl_xor(v.z, 4),
                                     __shfl_xor(v.w, 4));
        if (lane8 < 4) {   // this lane holds row yb, partner holds yb+1
            const int xg0 = lane8 * 4;
            float* dst = &S[c * CSTRIDE + xg0 * ZP + z];
            dst[0 * ZP] = wy0 * v.x + wy1 * o.x;
            dst[1 * ZP] = wy0 * v.y + wy1 * o.y;
            dst[2 * ZP] = wy0 * v.z + wy1 * o.z;
            dst[3 * ZP] = wy0 * v.w + wy1 * o.w;
        }
    }

    // ---- weights: compute BEFORE the barrier (only needs g4 + x) ----
    const float gvals[4] = {g4.x, g4.y, g4.z, g4.w};
    float w00[4], w01[4], w10[4], w11[4];
    int a0[4];
    #pragma unroll
    for (int p = 0; p < 4; ++p) {
        // z interpolation, clamped-base form
        const float gz  = gvals[p] * 8.0f;
        const float tz  = gz - 0.5f;
        const int   zb  = (int)fminf(fmaxf(floorf(tz), 0.0f), (float)(DD - 2));
        const float wz1 = fminf(fmaxf(tz - (float)zb, 0.0f), 1.0f);
        const float wz0 = 1.0f - wz1;

        // x interpolation, clamped-base form
        const float gx  = ((float)(x0 + p) + 0.5f) * (1.0f / 64.0f);
        const float tx  = gx - 0.5f;
        const int   xb  = (int)fminf(fmaxf(floorf(tx), 0.0f), (float)(WG - 2));
        const float wx1 = fminf(fmaxf(tx - (float)xb, 0.0f), 1.0f);
        const float wx0 = 1.0f - wx1;

        w00[p] = wx0 * wz0;
        w01[p] = wx0 * wz1;
        w10[p] = wx1 * wz0;
        w11[p] = wx1 * wz1;
        a0[p]  = xb * ZP + zb;
    }

    __syncthreads();

    float* outp = out + ((size_t)(b * CC) * HH + y) * WW + x0;

    #pragma unroll
    for (int c = 0; c < CC; ++c) {
        const float* base = S + c * CSTRIDE;
        float r[4];
        #pragma unroll
        for (int p = 0; p < 4; ++p) {
            const float va0 = base[a0[p]];          // (xb,   zb)
            const float va1 = base[a0[p] + 1];      // (xb,   zb+1)
            const float vb0 = base[a0[p] + ZP];     // (xb+1, zb)
            const float vb1 = base[a0[p] + ZP + 1]; // (xb+1, zb+1)
            r[p] = w00[p] * va0 + w01[p] * va1 + w10[p] * vb0 + w11[p] * vb1;
        }
        // nontemporal: output is never re-read — don't churn L2/L3 with it
        float4v o4 = { r[0], r[1], r[2], r[3] };
        __builtin_nontemporal_store(o4, (float4v*)(outp + (size_t)c * (HH * WW)));
    }
}

extern "C" void kernel_launch(void* const* d_in, const int* in_sizes, int n_in,
                              void* d_out, int out_size, void* d_ws, size_t ws_size,
                              hipStream_t stream) {
    const float* grid  = (const float*)d_in[0];  // 8*12*8*16*16
    const float* guide = (const float*)d_in[1];  // 8*1*1024*1024
    float* out = (float*)d_out;                  // 8*12*1024*1024

    slice_kernel<<<dim3(HH, BB), dim3(256), 0, stream>>>(grid, guide, out);
}